// Round 3
// baseline (773.981 us; speedup 1.0000x reference)
//
#include <hip/hip_runtime.h>
#include <hip/hip_bf16.h>

#define N_NODES 100000
#define N_EDGES 1600000
#define N_GRAPHS 1024
#define BSZ 1024
#define EPS 1e-5f

#define NBUCK 256
#define BUCKW 391          // ceil(100000/256); last bucket has 295 nodes
#define SRC_MASK 0x1FFFF   // 17 bits for src (<131072)
#define BIN_CHUNK 16384
#define BIN_BLOCKS 98      // ceil(1600000/16384)

// ---------------- workspace layout (4-byte units) ----------------
// zeroed-every-call region:
#define WS_GHIST   0          // 256 int
#define WS_BNAGG   256        // 256 (sum[128], sumsq[128]) of agg
#define WS_STATS1  512        // 128
#define WS_STATS2  640        // 128
#define WS_STATS4  768        // 512
#define WS_STATS5  1280       // 128
#define WS_ZTOTAL  1408
// written-before-read region:
#define WS_GBASE   1408       // 256 int
#define WS_GCUR    1664       // 256 int
#define WS_GSTART  1920       // 1025 int (pad to 2948)
#define WS_DIS     2948       // 100000 float
#define WS_PACKED  102948     // 1600000 u32
#define WS_SCALE1  1702948    // 128
#define WS_SHIFT1  1703076    // 128
#define WS_AGG     1703204    // 100000*128
#define WS_POOLED  14503204   // 1024*128
#define WS_T1      14634276   // 1024*64
#define WS_T2      14699812   // 1024*64
#define WS_T4      14765348   // 1024*256
#define WS_T5      15027492   // 1024*64
// total = 15093028 words = ~60.4 MB

__global__ void zero_kernel(float* __restrict__ p, int n) {
    int i = blockIdx.x * blockDim.x + threadIdx.x;
    int stride = gridDim.x * blockDim.x;
    for (; i < n; i += stride) p[i] = 0.0f;
}

// 256-bin histogram of dst buckets
__global__ __launch_bounds__(256) void hist_kernel(const int* __restrict__ dst,
                                                   int* __restrict__ ghist) {
    __shared__ int lh[NBUCK];
    int tid = threadIdx.x;
    lh[tid] = 0;
    __syncthreads();
    for (int i = blockIdx.x * 256 + tid; i < N_EDGES; i += gridDim.x * 256)
        atomicAdd(&lh[dst[i] / BUCKW], 1);
    __syncthreads();
    if (lh[tid]) atomicAdd(&ghist[tid], lh[tid]);
}

// exclusive scan of 256 bucket counts -> gbase, gcursor
__global__ __launch_bounds__(256) void scan_kernel(const int* __restrict__ ghist,
                                                   int* __restrict__ gbase,
                                                   int* __restrict__ gcursor) {
    __shared__ int ls[NBUCK];
    int tid = threadIdx.x;
    int v = ghist[tid];
    ls[tid] = v;
    for (int off = 1; off < NBUCK; off <<= 1) {
        __syncthreads();
        int t = (tid >= off) ? ls[tid - off] : 0;
        __syncthreads();
        ls[tid] += t;
    }
    __syncthreads();
    int excl = ls[tid] - v;
    gbase[tid] = excl;
    gcursor[tid] = excl;
}

// bin edges into 256 coarse buckets with LDS staging -> mostly-full-line writes
__global__ __launch_bounds__(1024) void bin_kernel(const int* __restrict__ ei,
                                                   int* __restrict__ gcursor,
                                                   unsigned int* __restrict__ packed) {
    __shared__ unsigned int stage[BIN_CHUNK];   // 64KB
    __shared__ int lh[NBUCK], lbase[NBUCK], lcur[NBUCK], gb[NBUCK];
    const int* src = ei;
    const int* dst = ei + N_EDGES;
    int tid = threadIdx.x;
    int base = blockIdx.x * BIN_CHUNK;
    int n = min(BIN_CHUNK, N_EDGES - base);
    if (tid < NBUCK) lh[tid] = 0;
    __syncthreads();
    for (int i = tid; i < n; i += 1024)
        atomicAdd(&lh[dst[base + i] / BUCKW], 1);
    __syncthreads();
    // inclusive scan of lh into lbase (256 lanes; all threads hit syncs)
    if (tid < NBUCK) lbase[tid] = lh[tid];
    __syncthreads();
    for (int off = 1; off < NBUCK; off <<= 1) {
        int t = (tid < NBUCK && tid >= off) ? lbase[tid - off] : 0;
        __syncthreads();
        if (tid < NBUCK) lbase[tid] += t;
        __syncthreads();
    }
    if (tid < NBUCK) {
        int excl = lbase[tid] - lh[tid];
        lbase[tid] = excl;
        lcur[tid] = excl;
        gb[tid] = atomicAdd(&gcursor[tid], lh[tid]);
    }
    __syncthreads();
    // place records into LDS ordered by bucket
    for (int i = tid; i < n; i += 1024) {
        int d = dst[base + i];
        int s = src[base + i];
        int bk = d / BUCKW;
        int dl = d - bk * BUCKW;
        int slot = atomicAdd(&lcur[bk], 1);
        stage[slot] = ((unsigned int)dl << 17) | (unsigned int)s;
    }
    __syncthreads();
    // flush contiguous per-bucket segments
    int wid = tid >> 6, lane = tid & 63;
    for (int bk = wid; bk < NBUCK; bk += 16) {
        int lo = lbase[bk], len = lh[bk], go = gb[bk];
        for (int j = lane; j < len; j += 64)
            packed[go + j] = stage[lo + j];
    }
}

// per-bucket degree histogram in LDS -> dis = rsqrt(deg+1)
__global__ __launch_bounds__(256) void degdis_kernel(const unsigned int* __restrict__ packed,
                                                     const int* __restrict__ gbase,
                                                     const int* __restrict__ ghist,
                                                     float* __restrict__ dis) {
    __shared__ int dcnt[BUCKW];
    int b = blockIdx.x, tid = threadIdx.x;
    for (int i = tid; i < BUCKW; i += 256) dcnt[i] = 0;
    __syncthreads();
    int e0 = gbase[b], n = ghist[b];
    for (int i = tid; i < n; i += 256)
        atomicAdd(&dcnt[packed[e0 + i] >> 17], 1);
    __syncthreads();
    int nbase = b * BUCKW;
    for (int i = tid; i < BUCKW; i += 256) {
        int node = nbase + i;
        if (node < N_NODES) dis[node] = rsqrtf((float)dcnt[i] + 1.0f);
    }
}

// per-bucket gather+aggregate in LDS, fused self-loop + (64->128 matvec W) + BN stats
__global__ __launch_bounds__(1024) void agg_kernel(const float* __restrict__ x,
                                                   const int* __restrict__ gbase,
                                                   const int* __restrict__ ghist,
                                                   const unsigned int* __restrict__ packed,
                                                   const float* __restrict__ dis,
                                                   const float* __restrict__ W,
                                                   const float* __restrict__ bgcn,
                                                   float* __restrict__ agg,
                                                   float* __restrict__ bnagg) {
    __shared__ float acc[BUCKW * 64];   // 100096 B
    __shared__ float Wl[64 * 128];      // 32768 B
    __shared__ float disl[BUCKW];       // 1564 B
    __shared__ float4 red[16][64];      // 16384 B   (total ~150.8 KB)
    int b = blockIdx.x;
    int tid = threadIdx.x;
    int wid = tid >> 6, lane = tid & 63;
    for (int i = tid; i < BUCKW * 64; i += 1024) acc[i] = 0.f;
    for (int i = tid; i < 64 * 128 / 4; i += 1024) ((float4*)Wl)[i] = ((const float4*)W)[i];
    int nbase = b * BUCKW;
    int nmax = min(BUCKW, N_NODES - nbase);
    for (int i = tid; i < nmax; i += 1024) disl[i] = dis[nbase + i];
    __syncthreads();
    int e0 = gbase[b], ecnt = ghist[b];
    for (int j0 = wid * 64; j0 < ecnt; j0 += 1024) {
        int cnt = min(64, ecnt - j0);
        unsigned int rec = 0;
        float dsv = 0.f;
        if (lane < cnt) {
            rec = packed[e0 + j0 + lane];
            dsv = dis[rec & SRC_MASK];
        }
        for (int k = 0; k < cnt; ++k) {
            unsigned int r = __shfl(rec, k);
            float ds = __shfl(dsv, k);
            int s = r & SRC_MASK;
            int dl = r >> 17;
            float nrm = ds * disl[dl];
            atomicAdd(&acc[dl * 64 + lane], x[(size_t)s * 64 + lane] * nrm);
        }
    }
    __syncthreads();
    // self-loop term (feature-parallel, race-free per row)
    for (int nl = wid; nl < nmax; nl += 16) {
        int node = nbase + nl;
        float dd = disl[nl];
        acc[nl * 64 + lane] += x[(size_t)node * 64 + lane] * dd * dd;
    }
    __syncthreads();
    // matvec 64->128 + bias, write agg, accumulate BN stats
    float2 bb = *(const float2*)(bgcn + 2 * lane);
    float s0 = 0.f, s1 = 0.f, q0 = 0.f, q1 = 0.f;
    for (int nl = wid; nl < nmax; nl += 16) {
        int node = nbase + nl;
        float r0 = bb.x, r1 = bb.y;
#pragma unroll 8
        for (int k = 0; k < 64; ++k) {
            float a = acc[nl * 64 + k];
            float2 w = ((const float2*)Wl)[k * 64 + lane];
            r0 += a * w.x;
            r1 += a * w.y;
        }
        *(float2*)(agg + (size_t)node * 128 + 2 * lane) = make_float2(r0, r1);
        s0 += r0; s1 += r1; q0 += r0 * r0; q1 += r1 * r1;
    }
    red[wid][lane] = make_float4(s0, s1, q0, q1);
    __syncthreads();
    if (tid < 64) {
        float S0 = 0.f, S1 = 0.f, Q0 = 0.f, Q1 = 0.f;
#pragma unroll
        for (int w = 0; w < 16; ++w) {
            float4 v = red[w][tid];
            S0 += v.x; S1 += v.y; Q0 += v.z; Q1 += v.w;
        }
        unsafeAtomicAdd(&bnagg[2 * tid], S0);
        unsafeAtomicAdd(&bnagg[2 * tid + 1], S1);
        unsafeAtomicAdd(&bnagg[128 + 2 * tid], Q0);
        unsafeAtomicAdd(&bnagg[128 + 2 * tid + 1], Q1);
    }
}

__global__ void bn1_fold_kernel(const float* __restrict__ stats, const float* __restrict__ g1,
                                const float* __restrict__ be1, float* __restrict__ scale1,
                                float* __restrict__ shift1) {
    int f = threadIdx.x;
    float m = stats[f] * (1.0f / N_NODES);
    float var = stats[128 + f] * (1.0f / N_NODES) - m * m;
    float sc = g1[f] * rsqrtf(var + EPS);
    scale1[f] = sc;
    shift1[f] = be1[f] - m * sc;
}

// gnn_batch is sorted: per-graph node ranges via binary search
__global__ __launch_bounds__(1024) void graph_bounds_kernel(const int* __restrict__ batch,
                                                            int* __restrict__ gstart) {
    int g = threadIdx.x;
    int lo = 0, hi = N_NODES;
    while (lo < hi) {
        int mid = (lo + hi) >> 1;
        if (batch[mid] < g) lo = mid + 1; else hi = mid;
    }
    gstart[g] = lo;
    if (g == 0) gstart[N_GRAPHS] = N_NODES;
}

// pooled[g] = mean over rows of relu(agg*scale1+shift1); one wave per graph
__global__ __launch_bounds__(256) void pool_gather_kernel(const float* __restrict__ agg,
                                                          const int* __restrict__ gstart,
                                                          const float* __restrict__ scale1,
                                                          const float* __restrict__ shift1,
                                                          float* __restrict__ pooled) {
    int g = (blockIdx.x * 256 + threadIdx.x) >> 6;
    int lane = threadIdx.x & 63;
    if (g >= N_GRAPHS) return;
    int r0 = gstart[g], r1 = gstart[g + 1];
    int f = lane * 2;
    float2 sc = *(const float2*)(scale1 + f);
    float2 sh = *(const float2*)(shift1 + f);
    float2 acc = {0.f, 0.f};
    for (int r = r0; r < r1; ++r) {
        float2 a = *(const float2*)(agg + (size_t)r * 128 + f);
        acc.x += fmaxf(a.x * sc.x + sh.x, 0.f);
        acc.y += fmaxf(a.y * sc.y + sh.y, 0.f);
    }
    float inv = 1.0f / fmaxf((float)(r1 - r0), 1.0f);
    float2 o; o.x = acc.x * inv; o.y = acc.y * inv;
    *(float2*)(pooled + (size_t)g * 128 + f) = o;
}

// t1 = pooled @ W_lin1 + b ; stats1 += (sum, sumsq)
__global__ __launch_bounds__(256) void lin1_kernel(const float* __restrict__ pooled,
                                                   const float* __restrict__ W,
                                                   const float* __restrict__ bias,
                                                   float* __restrict__ t1,
                                                   float* __restrict__ stats1) {
    __shared__ float ls[256], ls2[256];
    int tid = threadIdx.x;
    int r = blockIdx.x * 4 + (tid >> 6);
    int c = tid & 63;
    float acc = bias[c];
    const float* srow = pooled + (size_t)r * 128;
#pragma unroll 8
    for (int k = 0; k < 128; ++k)
        acc += srow[k] * W[k * 64 + c];
    t1[r * 64 + c] = acc;
    ls[tid] = acc; ls2[tid] = acc * acc;
    __syncthreads();
    if (tid < 64) {
        float s = ls[tid] + ls[tid + 64] + ls[tid + 128] + ls[tid + 192];
        float q = ls2[tid] + ls2[tid + 64] + ls2[tid + 128] + ls2[tid + 192];
        unsafeAtomicAdd(&stats1[c], s);
        unsafeAtomicAdd(&stats1[64 + c], q);
    }
}

// t2 = relu(bn(t1; g2,be2)) @ W_lin2 + b ; stats2
__global__ __launch_bounds__(256) void lin2_kernel(const float* __restrict__ t1,
                                                   const float* __restrict__ stats1,
                                                   const float* __restrict__ g,
                                                   const float* __restrict__ be,
                                                   const float* __restrict__ W,
                                                   const float* __restrict__ bias,
                                                   float* __restrict__ t2,
                                                   float* __restrict__ stats2) {
    __shared__ float sc[64], sh[64];
    __shared__ float ls[256], ls2[256];
    int tid = threadIdx.x;
    if (tid < 64) {
        float m = stats1[tid] * (1.0f / BSZ);
        float var = stats1[64 + tid] * (1.0f / BSZ) - m * m;
        float s = g[tid] * rsqrtf(var + EPS);
        sc[tid] = s; sh[tid] = be[tid] - m * s;
    }
    __syncthreads();
    int r = blockIdx.x * 4 + (tid >> 6);
    int c = tid & 63;
    float acc = bias[c];
    const float* row = t1 + (size_t)r * 64;
#pragma unroll 8
    for (int k = 0; k < 64; ++k) {
        float z = fmaxf(row[k] * sc[k] + sh[k], 0.f);
        acc += z * W[k * 64 + c];
    }
    t2[r * 64 + c] = acc;
    ls[tid] = acc; ls2[tid] = acc * acc;
    __syncthreads();
    if (tid < 64) {
        float s = ls[tid] + ls[tid + 64] + ls[tid + 128] + ls[tid + 192];
        float q = ls2[tid] + ls2[tid + 64] + ls2[tid + 128] + ls2[tid + 192];
        unsafeAtomicAdd(&stats2[c], s);
        unsafeAtomicAdd(&stats2[64 + c], q);
    }
}

// t4 = concat(x, bn(t2;g3,be3)[masks]) @ W_fc1 + b ; stats4
__global__ __launch_bounds__(1024) void fc1_kernel(const float* __restrict__ x,
                                                   const int* __restrict__ masks,
                                                   const float* __restrict__ t2,
                                                   const float* __restrict__ stats2,
                                                   const float* __restrict__ g3,
                                                   const float* __restrict__ be3,
                                                   const float* __restrict__ W,
                                                   const float* __restrict__ bias,
                                                   float* __restrict__ t4,
                                                   float* __restrict__ stats4) {
    __shared__ float sc[64], sh[64];
    __shared__ float cat[4][128];
    __shared__ float ls[1024], ls2[1024];
    int tid = threadIdx.x;
    if (tid < 64) {
        float m = stats2[tid] * (1.0f / BSZ);
        float var = stats2[64 + tid] * (1.0f / BSZ) - m * m;
        float s = g3[tid] * rsqrtf(var + EPS);
        sc[tid] = s; sh[tid] = be3[tid] - m * s;
    }
    __syncthreads();
    int r0 = blockIdx.x * 4;
    if (tid < 512) {
        int i = tid >> 7;
        int k = tid & 127;
        int r = r0 + i;
        float v;
        if (k < 64) {
            v = x[r * 64 + k];
        } else {
            int mrow = masks[r];
            int kk = k - 64;
            v = t2[mrow * 64 + kk] * sc[kk] + sh[kk];
        }
        cat[i][k] = v;
    }
    __syncthreads();
    int i = tid >> 8;
    int c = tid & 255;
    float acc = bias[c];
#pragma unroll 8
    for (int k = 0; k < 128; ++k)
        acc += cat[i][k] * W[k * 256 + c];
    t4[(size_t)(r0 + i) * 256 + c] = acc;
    ls[tid] = acc; ls2[tid] = acc * acc;
    __syncthreads();
    if (tid < 256) {
        float s = ls[tid] + ls[tid + 256] + ls[tid + 512] + ls[tid + 768];
        float q = ls2[tid] + ls2[tid + 256] + ls2[tid + 512] + ls2[tid + 768];
        unsafeAtomicAdd(&stats4[c], s);
        unsafeAtomicAdd(&stats4[256 + c], q);
    }
}

// t5 = (relu(bn(t4;g4,be4))^2) @ W_fc2 + b ; stats5
__global__ __launch_bounds__(256) void fc2_kernel(const float* __restrict__ t4,
                                                  const float* __restrict__ stats4,
                                                  const float* __restrict__ g4,
                                                  const float* __restrict__ be4,
                                                  const float* __restrict__ W,
                                                  const float* __restrict__ bias,
                                                  float* __restrict__ t5,
                                                  float* __restrict__ stats5) {
    __shared__ float sc[256], sh[256];
    __shared__ float ls[256], ls2[256];
    int tid = threadIdx.x;
    {
        float m = stats4[tid] * (1.0f / BSZ);
        float var = stats4[256 + tid] * (1.0f / BSZ) - m * m;
        float s = g4[tid] * rsqrtf(var + EPS);
        sc[tid] = s; sh[tid] = be4[tid] - m * s;
    }
    __syncthreads();
    int r = blockIdx.x * 4 + (tid >> 6);
    int c = tid & 63;
    float acc = bias[c];
    const float* row = t4 + (size_t)r * 256;
#pragma unroll 8
    for (int k = 0; k < 256; ++k) {
        float z = fmaxf(row[k] * sc[k] + sh[k], 0.f);
        z *= z;
        acc += z * W[k * 64 + c];
    }
    t5[r * 64 + c] = acc;
    ls[tid] = acc; ls2[tid] = acc * acc;
    __syncthreads();
    if (tid < 64) {
        float s = ls[tid] + ls[tid + 64] + ls[tid + 128] + ls[tid + 192];
        float q = ls2[tid] + ls2[tid + 64] + ls2[tid + 128] + ls2[tid + 192];
        unsafeAtomicAdd(&stats5[c], s);
        unsafeAtomicAdd(&stats5[64 + c], q);
    }
}

// out = ((relu(bn(t5;g5,be5)))^4) @ W_fc3 + b
__global__ __launch_bounds__(256) void fc3_kernel(const float* __restrict__ t5,
                                                  const float* __restrict__ stats5,
                                                  const float* __restrict__ g5,
                                                  const float* __restrict__ be5,
                                                  const float* __restrict__ W,
                                                  const float* __restrict__ bias,
                                                  float* __restrict__ out) {
    __shared__ float sc[64], sh[64];
    int tid = threadIdx.x;
    if (tid < 64) {
        float m = stats5[tid] * (1.0f / BSZ);
        float var = stats5[64 + tid] * (1.0f / BSZ) - m * m;
        float s = g5[tid] * rsqrtf(var + EPS);
        sc[tid] = s; sh[tid] = be5[tid] - m * s;
    }
    __syncthreads();
    int r = blockIdx.x * 256 + tid;
    float acc = bias[0];
    const float* row = t5 + (size_t)r * 64;
#pragma unroll
    for (int k = 0; k < 64; ++k) {
        float z = fmaxf(row[k] * sc[k] + sh[k], 0.f);
        z = z * z;
        z = z * z;
        acc += z * W[k];
    }
    out[r] = acc;
}

extern "C" void kernel_launch(void* const* d_in, const int* in_sizes, int n_in,
                              void* d_out, int out_size, void* d_ws, size_t ws_size,
                              hipStream_t stream) {
    const float* x      = (const float*)d_in[0];
    const int*   masks  = (const int*)d_in[1];
    const float* gnn_x  = (const float*)d_in[2];
    const int*   ei     = (const int*)d_in[3];
    const int*   gbatch = (const int*)d_in[4];
    const float* W_gcn  = (const float*)d_in[5];
    const float* b_gcn  = (const float*)d_in[6];
    const float* g1     = (const float*)d_in[7];
    const float* be1    = (const float*)d_in[8];
    const float* W_lin1 = (const float*)d_in[9];
    const float* b_lin1 = (const float*)d_in[10];
    const float* g2     = (const float*)d_in[11];
    const float* be2    = (const float*)d_in[12];
    const float* W_lin2 = (const float*)d_in[13];
    const float* b_lin2 = (const float*)d_in[14];
    const float* g3     = (const float*)d_in[15];
    const float* be3    = (const float*)d_in[16];
    const float* W_fc1  = (const float*)d_in[17];
    const float* b_fc1  = (const float*)d_in[18];
    const float* g4     = (const float*)d_in[19];
    const float* be4    = (const float*)d_in[20];
    const float* W_fc2  = (const float*)d_in[21];
    const float* b_fc2  = (const float*)d_in[22];
    const float* g5     = (const float*)d_in[23];
    const float* be5    = (const float*)d_in[24];
    const float* W_fc3  = (const float*)d_in[25];
    const float* b_fc3  = (const float*)d_in[26];

    float* ws = (float*)d_ws;
    int*   ghist  = (int*)(ws + WS_GHIST);
    float* bnagg  = ws + WS_BNAGG;
    float* stats1 = ws + WS_STATS1;
    float* stats2 = ws + WS_STATS2;
    float* stats4 = ws + WS_STATS4;
    float* stats5 = ws + WS_STATS5;
    int*   gbase  = (int*)(ws + WS_GBASE);
    int*   gcur   = (int*)(ws + WS_GCUR);
    int*   gstart = (int*)(ws + WS_GSTART);
    float* dis    = ws + WS_DIS;
    unsigned int* packed = (unsigned int*)(ws + WS_PACKED);
    float* scale1 = ws + WS_SCALE1;
    float* shift1 = ws + WS_SHIFT1;
    float* agg    = ws + WS_AGG;
    float* pooled = ws + WS_POOLED;
    float* t1     = ws + WS_T1;
    float* t2     = ws + WS_T2;
    float* t4     = ws + WS_T4;
    float* t5     = ws + WS_T5;
    float* out    = (float*)d_out;

    zero_kernel<<<6, 256, 0, stream>>>(ws, WS_ZTOTAL);
    hist_kernel<<<256, 256, 0, stream>>>(ei + N_EDGES, ghist);
    scan_kernel<<<1, 256, 0, stream>>>(ghist, gbase, gcur);
    bin_kernel<<<BIN_BLOCKS, 1024, 0, stream>>>(ei, gcur, packed);
    degdis_kernel<<<NBUCK, 256, 0, stream>>>(packed, gbase, ghist, dis);
    agg_kernel<<<NBUCK, 1024, 0, stream>>>(gnn_x, gbase, ghist, packed, dis, W_gcn, b_gcn, agg, bnagg);
    bn1_fold_kernel<<<1, 128, 0, stream>>>(bnagg, g1, be1, scale1, shift1);
    graph_bounds_kernel<<<1, 1024, 0, stream>>>(gbatch, gstart);
    pool_gather_kernel<<<(N_GRAPHS * 64 + 255) / 256, 256, 0, stream>>>(agg, gstart, scale1, shift1, pooled);
    lin1_kernel<<<256, 256, 0, stream>>>(pooled, W_lin1, b_lin1, t1, stats1);
    lin2_kernel<<<256, 256, 0, stream>>>(t1, stats1, g2, be2, W_lin2, b_lin2, t2, stats2);
    fc1_kernel<<<256, 1024, 0, stream>>>(x, masks, t2, stats2, g3, be3, W_fc1, b_fc1, t4, stats4);
    fc2_kernel<<<256, 256, 0, stream>>>(t4, stats4, g4, be4, W_fc2, b_fc2, t5, stats5);
    fc3_kernel<<<4, 256, 0, stream>>>(t5, stats5, g5, be5, W_fc3, b_fc3, out);
}

// Round 4
// 295.303 us; speedup vs baseline: 2.6210x; 2.6210x over previous
//
#include <hip/hip_runtime.h>
#include <hip/hip_bf16.h>

#define N_NODES 100000
#define N_EDGES 1600000
#define N_GRAPHS 1024
#define BSZ 1024
#define EPS 1e-5f

#define NBUCK 256
#define BUCKW 391          // ceil(100000/256); last bucket has 295 nodes
#define SRC_MASK 0x1FFFF   // 17 bits for src (<131072)
#define BIN_CHUNK 16384
#define BIN_BLOCKS 98      // ceil(1600000/16384)
#define STAGE_CAP 16384    // per-bucket LDS sort capacity (avg bucket ~6250)

// ---------------- workspace layout (4-byte units) ----------------
// zeroed-every-call region:
#define WS_GHIST   0          // 256 int
#define WS_BNAGG   256        // 256 (sum[128], sumsq[128]) of agg
#define WS_STATS1  512        // 128
#define WS_STATS2  640        // 128
#define WS_STATS4  768        // 512
#define WS_STATS5  1280       // 128
#define WS_ZTOTAL  1408
// written-before-read region:
#define WS_GBASE   1408       // 256 int
#define WS_GCUR    1664       // 256 int
#define WS_GSTART  1920       // 1025 int (pad to 2948)
#define WS_DIS     2948       // 100000 float
#define WS_ROWPTR  102948     // 100001 int (pad to 202952)
#define WS_PACKED  202952     // 1600000 u32
#define WS_CSRC    1802952    // 1600000 int (exact CSR src, sorted by dst)
#define WS_SCALE1  3402952    // 128
#define WS_SHIFT1  3403080    // 128
#define WS_AGGX    3403208    // 100000*64
#define WS_AGG     9803208    // 100000*128
#define WS_POOLED  22603208   // 1024*128
#define WS_T1      22734280   // 1024*64
#define WS_T2      22799816   // 1024*64
#define WS_T4      22865352   // 1024*256
#define WS_T5      23127496   // 1024*64
// total = 23193032 words = ~92.8 MB

__global__ void zero_kernel(float* __restrict__ p, int n) {
    int i = blockIdx.x * blockDim.x + threadIdx.x;
    int stride = gridDim.x * blockDim.x;
    for (; i < n; i += stride) p[i] = 0.0f;
}

// 256-bin histogram of dst buckets
__global__ __launch_bounds__(256) void hist_kernel(const int* __restrict__ dst,
                                                   int* __restrict__ ghist) {
    __shared__ int lh[NBUCK];
    int tid = threadIdx.x;
    lh[tid] = 0;
    __syncthreads();
    for (int i = blockIdx.x * 256 + tid; i < N_EDGES; i += gridDim.x * 256)
        atomicAdd(&lh[dst[i] / BUCKW], 1);
    __syncthreads();
    if (lh[tid]) atomicAdd(&ghist[tid], lh[tid]);
}

// exclusive scan of 256 bucket counts -> gbase, gcursor
__global__ __launch_bounds__(256) void scan_kernel(const int* __restrict__ ghist,
                                                   int* __restrict__ gbase,
                                                   int* __restrict__ gcursor) {
    __shared__ int ls[NBUCK];
    int tid = threadIdx.x;
    int v = ghist[tid];
    ls[tid] = v;
    for (int off = 1; off < NBUCK; off <<= 1) {
        __syncthreads();
        int t = (tid >= off) ? ls[tid - off] : 0;
        __syncthreads();
        ls[tid] += t;
    }
    __syncthreads();
    int excl = ls[tid] - v;
    gbase[tid] = excl;
    gcursor[tid] = excl;
}

// bin edges into 256 coarse buckets with LDS staging -> mostly-full-line writes
__global__ __launch_bounds__(1024) void bin_kernel(const int* __restrict__ ei,
                                                   int* __restrict__ gcursor,
                                                   unsigned int* __restrict__ packed) {
    __shared__ unsigned int stage[BIN_CHUNK];   // 64KB
    __shared__ int lh[NBUCK], lbase[NBUCK], lcur[NBUCK], gb[NBUCK];
    const int* src = ei;
    const int* dst = ei + N_EDGES;
    int tid = threadIdx.x;
    int base = blockIdx.x * BIN_CHUNK;
    int n = min(BIN_CHUNK, N_EDGES - base);
    if (tid < NBUCK) lh[tid] = 0;
    __syncthreads();
    for (int i = tid; i < n; i += 1024)
        atomicAdd(&lh[dst[base + i] / BUCKW], 1);
    __syncthreads();
    if (tid < NBUCK) lbase[tid] = lh[tid];
    __syncthreads();
    for (int off = 1; off < NBUCK; off <<= 1) {
        int t = (tid < NBUCK && tid >= off) ? lbase[tid - off] : 0;
        __syncthreads();
        if (tid < NBUCK) lbase[tid] += t;
        __syncthreads();
    }
    if (tid < NBUCK) {
        int excl = lbase[tid] - lh[tid];
        lbase[tid] = excl;
        lcur[tid] = excl;
        gb[tid] = atomicAdd(&gcursor[tid], lh[tid]);
    }
    __syncthreads();
    for (int i = tid; i < n; i += 1024) {
        int d = dst[base + i];
        int s = src[base + i];
        int bk = d / BUCKW;
        int dl = d - bk * BUCKW;
        int slot = atomicAdd(&lcur[bk], 1);
        stage[slot] = ((unsigned int)dl << 17) | (unsigned int)s;
    }
    __syncthreads();
    int wid = tid >> 6, lane = tid & 63;
    for (int bk = wid; bk < NBUCK; bk += 16) {
        int lo = lbase[bk], len = lh[bk], go = gb[bk];
        for (int j = lane; j < len; j += 64)
            packed[go + j] = stage[lo + j];
    }
}

// per-bucket: exact CSR (sorted in LDS, coalesced write) + rowptr + dis
__global__ __launch_bounds__(256) void csr_build_kernel(const unsigned int* __restrict__ packed,
                                                        const int* __restrict__ gbase,
                                                        const int* __restrict__ ghist,
                                                        int* __restrict__ rowptr,
                                                        int* __restrict__ csrc,
                                                        float* __restrict__ dis) {
    __shared__ int dcnt[BUCKW];       // deg histogram, then excl scan
    __shared__ int lcur[BUCKW];       // scatter cursors
    __shared__ int stage[STAGE_CAP];  // 64KB sorted srcs
    int b = blockIdx.x, tid = threadIdx.x;
    int e0 = gbase[b], ecnt = ghist[b];
    int nbase = b * BUCKW;
    int nmax = min(BUCKW, N_NODES - nbase);
    for (int i = tid; i < BUCKW; i += 256) dcnt[i] = 0;
    __syncthreads();
    for (int i = tid; i < ecnt; i += 256)
        atomicAdd(&dcnt[packed[e0 + i] >> 17], 1);
    __syncthreads();
    for (int i = tid; i < nmax; i += 256)
        dis[nbase + i] = rsqrtf((float)dcnt[i] + 1.0f);
    __syncthreads();
    // exclusive scan of dcnt by wave 0 (7 chunks of 64)
    if (tid < 64) {
        int lane = tid;
        int run = 0;
        for (int c = 0; c < BUCKW; c += 64) {
            int idx = c + lane;
            int v = (idx < BUCKW) ? dcnt[idx] : 0;
            int inc = v;
#pragma unroll
            for (int off = 1; off < 64; off <<= 1) {
                int t = __shfl_up(inc, off);
                if (lane >= off) inc += t;
            }
            if (idx < BUCKW) {
                int excl = run + inc - v;
                dcnt[idx] = excl;
                lcur[idx] = excl;
            }
            run += __shfl(inc, 63);
        }
    }
    __syncthreads();
    for (int i = tid; i < nmax; i += 256)
        rowptr[nbase + i] = e0 + dcnt[i];
    if (b == 0 && tid == 0) rowptr[N_NODES] = N_EDGES;
    if (ecnt <= STAGE_CAP) {
        for (int i = tid; i < ecnt; i += 256) {
            unsigned int r = packed[e0 + i];
            int slot = atomicAdd(&lcur[r >> 17], 1);
            stage[slot] = (int)(r & SRC_MASK);
        }
        __syncthreads();
        for (int i = tid; i < ecnt; i += 256) csrc[e0 + i] = stage[i];
    } else {  // safety fallback (never expected with uniform dsts)
        for (int i = tid; i < ecnt; i += 256) {
            unsigned int r = packed[e0 + i];
            int slot = atomicAdd(&lcur[r >> 17], 1);
            csrc[e0 + slot] = (int)(r & SRC_MASK);
        }
    }
}

// aggx[n] = x[n]*dis[n]^2 + sum_{s in in(n)} x[s]*dis[s]*dis[n]
// one wave per node, 8-deep pipelined gather
__global__ __launch_bounds__(256) void gather_kernel(const float* __restrict__ x,
                                                     const int* __restrict__ rowptr,
                                                     const int* __restrict__ csrc,
                                                     const float* __restrict__ dis,
                                                     float* __restrict__ aggx) {
    int wid = (blockIdx.x * 256 + threadIdx.x) >> 6;
    int lane = threadIdx.x & 63;
    if (wid >= N_NODES) return;
    int start = rowptr[wid];
    int end = rowptr[wid + 1];
    float dd = dis[wid];
    float acc = x[(size_t)wid * 64 + lane] * dd * dd;
    for (int j0 = start; j0 < end; j0 += 64) {
        int cnt = min(64, end - j0);
        int sv = 0;
        float wv = 0.f;
        if (lane < cnt) {
            sv = csrc[j0 + lane];
            wv = dis[sv] * dd;
        }
        int iters = (cnt + 7) & ~7;
        for (int k = 0; k < iters; k += 8) {
            int s[8]; float w[8], v[8];
#pragma unroll
            for (int u = 0; u < 8; ++u) {
                s[u] = __shfl(sv, k + u);
                w[u] = __shfl(wv, k + u);
            }
#pragma unroll
            for (int u = 0; u < 8; ++u) v[u] = x[(size_t)s[u] * 64 + lane];
#pragma unroll
            for (int u = 0; u < 8; ++u) acc = fmaf(v[u], w[u], acc);
        }
    }
    aggx[(size_t)wid * 64 + lane] = acc;
}

// agg[100000,128] = aggx[100000,64] @ W_gcn[64,128] + b_gcn
__global__ __launch_bounds__(256) void gemm_agg_kernel(const float* __restrict__ A,
                                                       const float* __restrict__ W,
                                                       const float* __restrict__ bias,
                                                       float* __restrict__ AGG) {
    __shared__ float Ws[64 * 128];
    __shared__ float As[16 * 64];
    int tid = threadIdx.x;
    const float4* W4 = (const float4*)W;
    float4* Ws4 = (float4*)Ws;
#pragma unroll
    for (int i = 0; i < 8; ++i) Ws4[tid + i * 256] = W4[tid + i * 256];
    int row0 = blockIdx.x * 16;
    ((float4*)As)[tid] = ((const float4*)(A + (size_t)row0 * 64))[tid];
    __syncthreads();
    int tx = tid & 31;
    int ty = tid >> 5;
    int r0 = ty * 2;
    float4 bb = ((const float4*)bias)[tx];
    float acc[2][4] = {{bb.x, bb.y, bb.z, bb.w}, {bb.x, bb.y, bb.z, bb.w}};
#pragma unroll
    for (int k = 0; k < 64; ++k) {
        float a0 = As[r0 * 64 + k];
        float a1 = As[(r0 + 1) * 64 + k];
        float4 w = Ws4[k * 32 + tx];
        acc[0][0] += a0 * w.x; acc[0][1] += a0 * w.y; acc[0][2] += a0 * w.z; acc[0][3] += a0 * w.w;
        acc[1][0] += a1 * w.x; acc[1][1] += a1 * w.y; acc[1][2] += a1 * w.z; acc[1][3] += a1 * w.w;
    }
#pragma unroll
    for (int rr = 0; rr < 2; ++rr) {
        float4 v = make_float4(acc[rr][0], acc[rr][1], acc[rr][2], acc[rr][3]);
        ((float4*)(AGG + (size_t)(row0 + r0 + rr) * 128))[tx] = v;
    }
}

__global__ __launch_bounds__(256) void bnagg_stats_kernel(const float* __restrict__ agg,
                                                          float* __restrict__ stats) {
    __shared__ float4 ls[256];
    int tid = threadIdx.x;
    int lane = tid & 63;
    int grp = tid >> 6;
    int f = lane * 2;
    float2 s = {0.f, 0.f}, sq = {0.f, 0.f};
    for (int r = blockIdx.x * 4 + grp; r < N_NODES; r += gridDim.x * 4) {
        float2 a = *(const float2*)(agg + (size_t)r * 128 + f);
        s.x += a.x; s.y += a.y;
        sq.x += a.x * a.x; sq.y += a.y * a.y;
    }
    ls[tid] = make_float4(s.x, s.y, sq.x, sq.y);
    __syncthreads();
    if (tid < 64) {
        float4 v = ls[tid];
        float4 b = ls[tid + 64], c = ls[tid + 128], d = ls[tid + 192];
        v.x += b.x + c.x + d.x;
        v.y += b.y + c.y + d.y;
        v.z += b.z + c.z + d.z;
        v.w += b.w + c.w + d.w;
        unsafeAtomicAdd(&stats[f], v.x);
        unsafeAtomicAdd(&stats[f + 1], v.y);
        unsafeAtomicAdd(&stats[128 + f], v.z);
        unsafeAtomicAdd(&stats[128 + f + 1], v.w);
    }
}

__global__ void bn1_fold_kernel(const float* __restrict__ stats, const float* __restrict__ g1,
                                const float* __restrict__ be1, float* __restrict__ scale1,
                                float* __restrict__ shift1) {
    int f = threadIdx.x;
    float m = stats[f] * (1.0f / N_NODES);
    float var = stats[128 + f] * (1.0f / N_NODES) - m * m;
    float sc = g1[f] * rsqrtf(var + EPS);
    scale1[f] = sc;
    shift1[f] = be1[f] - m * sc;
}

// gnn_batch is sorted: per-graph node ranges via binary search
__global__ __launch_bounds__(1024) void graph_bounds_kernel(const int* __restrict__ batch,
                                                            int* __restrict__ gstart) {
    int g = threadIdx.x;
    int lo = 0, hi = N_NODES;
    while (lo < hi) {
        int mid = (lo + hi) >> 1;
        if (batch[mid] < g) lo = mid + 1; else hi = mid;
    }
    gstart[g] = lo;
    if (g == 0) gstart[N_GRAPHS] = N_NODES;
}

// pooled[g] = mean over rows of relu(agg*scale1+shift1); one wave per graph
__global__ __launch_bounds__(256) void pool_gather_kernel(const float* __restrict__ agg,
                                                          const int* __restrict__ gstart,
                                                          const float* __restrict__ scale1,
                                                          const float* __restrict__ shift1,
                                                          float* __restrict__ pooled) {
    int g = (blockIdx.x * 256 + threadIdx.x) >> 6;
    int lane = threadIdx.x & 63;
    if (g >= N_GRAPHS) return;
    int r0 = gstart[g], r1 = gstart[g + 1];
    int f = lane * 2;
    float2 sc = *(const float2*)(scale1 + f);
    float2 sh = *(const float2*)(shift1 + f);
    float2 acc = {0.f, 0.f};
    for (int r = r0; r < r1; ++r) {
        float2 a = *(const float2*)(agg + (size_t)r * 128 + f);
        acc.x += fmaxf(a.x * sc.x + sh.x, 0.f);
        acc.y += fmaxf(a.y * sc.y + sh.y, 0.f);
    }
    float inv = 1.0f / fmaxf((float)(r1 - r0), 1.0f);
    float2 o; o.x = acc.x * inv; o.y = acc.y * inv;
    *(float2*)(pooled + (size_t)g * 128 + f) = o;
}

// t1 = pooled @ W_lin1 + b ; stats1 += (sum, sumsq)
__global__ __launch_bounds__(256) void lin1_kernel(const float* __restrict__ pooled,
                                                   const float* __restrict__ W,
                                                   const float* __restrict__ bias,
                                                   float* __restrict__ t1,
                                                   float* __restrict__ stats1) {
    __shared__ float ls[256], ls2[256];
    int tid = threadIdx.x;
    int r = blockIdx.x * 4 + (tid >> 6);
    int c = tid & 63;
    float acc = bias[c];
    const float* srow = pooled + (size_t)r * 128;
#pragma unroll 8
    for (int k = 0; k < 128; ++k)
        acc += srow[k] * W[k * 64 + c];
    t1[r * 64 + c] = acc;
    ls[tid] = acc; ls2[tid] = acc * acc;
    __syncthreads();
    if (tid < 64) {
        float s = ls[tid] + ls[tid + 64] + ls[tid + 128] + ls[tid + 192];
        float q = ls2[tid] + ls2[tid + 64] + ls2[tid + 128] + ls2[tid + 192];
        unsafeAtomicAdd(&stats1[c], s);
        unsafeAtomicAdd(&stats1[64 + c], q);
    }
}

// t2 = relu(bn(t1; g2,be2)) @ W_lin2 + b ; stats2
__global__ __launch_bounds__(256) void lin2_kernel(const float* __restrict__ t1,
                                                   const float* __restrict__ stats1,
                                                   const float* __restrict__ g,
                                                   const float* __restrict__ be,
                                                   const float* __restrict__ W,
                                                   const float* __restrict__ bias,
                                                   float* __restrict__ t2,
                                                   float* __restrict__ stats2) {
    __shared__ float sc[64], sh[64];
    __shared__ float ls[256], ls2[256];
    int tid = threadIdx.x;
    if (tid < 64) {
        float m = stats1[tid] * (1.0f / BSZ);
        float var = stats1[64 + tid] * (1.0f / BSZ) - m * m;
        float s = g[tid] * rsqrtf(var + EPS);
        sc[tid] = s; sh[tid] = be[tid] - m * s;
    }
    __syncthreads();
    int r = blockIdx.x * 4 + (tid >> 6);
    int c = tid & 63;
    float acc = bias[c];
    const float* row = t1 + (size_t)r * 64;
#pragma unroll 8
    for (int k = 0; k < 64; ++k) {
        float z = fmaxf(row[k] * sc[k] + sh[k], 0.f);
        acc += z * W[k * 64 + c];
    }
    t2[r * 64 + c] = acc;
    ls[tid] = acc; ls2[tid] = acc * acc;
    __syncthreads();
    if (tid < 64) {
        float s = ls[tid] + ls[tid + 64] + ls[tid + 128] + ls[tid + 192];
        float q = ls2[tid] + ls2[tid + 64] + ls2[tid + 128] + ls2[tid + 192];
        unsafeAtomicAdd(&stats2[c], s);
        unsafeAtomicAdd(&stats2[64 + c], q);
    }
}

// t4 = concat(x, bn(t2;g3,be3)[masks]) @ W_fc1 + b ; stats4
__global__ __launch_bounds__(1024) void fc1_kernel(const float* __restrict__ x,
                                                   const int* __restrict__ masks,
                                                   const float* __restrict__ t2,
                                                   const float* __restrict__ stats2,
                                                   const float* __restrict__ g3,
                                                   const float* __restrict__ be3,
                                                   const float* __restrict__ W,
                                                   const float* __restrict__ bias,
                                                   float* __restrict__ t4,
                                                   float* __restrict__ stats4) {
    __shared__ float sc[64], sh[64];
    __shared__ float cat[4][128];
    __shared__ float ls[1024], ls2[1024];
    int tid = threadIdx.x;
    if (tid < 64) {
        float m = stats2[tid] * (1.0f / BSZ);
        float var = stats2[64 + tid] * (1.0f / BSZ) - m * m;
        float s = g3[tid] * rsqrtf(var + EPS);
        sc[tid] = s; sh[tid] = be3[tid] - m * s;
    }
    __syncthreads();
    int r0 = blockIdx.x * 4;
    if (tid < 512) {
        int i = tid >> 7;
        int k = tid & 127;
        int r = r0 + i;
        float v;
        if (k < 64) {
            v = x[r * 64 + k];
        } else {
            int mrow = masks[r];
            int kk = k - 64;
            v = t2[mrow * 64 + kk] * sc[kk] + sh[kk];
        }
        cat[i][k] = v;
    }
    __syncthreads();
    int i = tid >> 8;
    int c = tid & 255;
    float acc = bias[c];
#pragma unroll 8
    for (int k = 0; k < 128; ++k)
        acc += cat[i][k] * W[k * 256 + c];
    t4[(size_t)(r0 + i) * 256 + c] = acc;
    ls[tid] = acc; ls2[tid] = acc * acc;
    __syncthreads();
    if (tid < 256) {
        float s = ls[tid] + ls[tid + 256] + ls[tid + 512] + ls[tid + 768];
        float q = ls2[tid] + ls2[tid + 256] + ls2[tid + 512] + ls2[tid + 768];
        unsafeAtomicAdd(&stats4[c], s);
        unsafeAtomicAdd(&stats4[256 + c], q);
    }
}

// t5 = (relu(bn(t4;g4,be4))^2) @ W_fc2 + b ; stats5
__global__ __launch_bounds__(256) void fc2_kernel(const float* __restrict__ t4,
                                                  const float* __restrict__ stats4,
                                                  const float* __restrict__ g4,
                                                  const float* __restrict__ be4,
                                                  const float* __restrict__ W,
                                                  const float* __restrict__ bias,
                                                  float* __restrict__ t5,
                                                  float* __restrict__ stats5) {
    __shared__ float sc[256], sh[256];
    __shared__ float ls[256], ls2[256];
    int tid = threadIdx.x;
    {
        float m = stats4[tid] * (1.0f / BSZ);
        float var = stats4[256 + tid] * (1.0f / BSZ) - m * m;
        float s = g4[tid] * rsqrtf(var + EPS);
        sc[tid] = s; sh[tid] = be4[tid] - m * s;
    }
    __syncthreads();
    int r = blockIdx.x * 4 + (tid >> 6);
    int c = tid & 63;
    float acc = bias[c];
    const float* row = t4 + (size_t)r * 256;
#pragma unroll 8
    for (int k = 0; k < 256; ++k) {
        float z = fmaxf(row[k] * sc[k] + sh[k], 0.f);
        z *= z;
        acc += z * W[k * 64 + c];
    }
    t5[r * 64 + c] = acc;
    ls[tid] = acc; ls2[tid] = acc * acc;
    __syncthreads();
    if (tid < 64) {
        float s = ls[tid] + ls[tid + 64] + ls[tid + 128] + ls[tid + 192];
        float q = ls2[tid] + ls2[tid + 64] + ls2[tid + 128] + ls2[tid + 192];
        unsafeAtomicAdd(&stats5[c], s);
        unsafeAtomicAdd(&stats5[64 + c], q);
    }
}

// out = ((relu(bn(t5;g5,be5)))^4) @ W_fc3 + b
__global__ __launch_bounds__(256) void fc3_kernel(const float* __restrict__ t5,
                                                  const float* __restrict__ stats5,
                                                  const float* __restrict__ g5,
                                                  const float* __restrict__ be5,
                                                  const float* __restrict__ W,
                                                  const float* __restrict__ bias,
                                                  float* __restrict__ out) {
    __shared__ float sc[64], sh[64];
    int tid = threadIdx.x;
    if (tid < 64) {
        float m = stats5[tid] * (1.0f / BSZ);
        float var = stats5[64 + tid] * (1.0f / BSZ) - m * m;
        float s = g5[tid] * rsqrtf(var + EPS);
        sc[tid] = s; sh[tid] = be5[tid] - m * s;
    }
    __syncthreads();
    int r = blockIdx.x * 256 + tid;
    float acc = bias[0];
    const float* row = t5 + (size_t)r * 64;
#pragma unroll
    for (int k = 0; k < 64; ++k) {
        float z = fmaxf(row[k] * sc[k] + sh[k], 0.f);
        z = z * z;
        z = z * z;
        acc += z * W[k];
    }
    out[r] = acc;
}

extern "C" void kernel_launch(void* const* d_in, const int* in_sizes, int n_in,
                              void* d_out, int out_size, void* d_ws, size_t ws_size,
                              hipStream_t stream) {
    const float* x      = (const float*)d_in[0];
    const int*   masks  = (const int*)d_in[1];
    const float* gnn_x  = (const float*)d_in[2];
    const int*   ei     = (const int*)d_in[3];
    const int*   gbatch = (const int*)d_in[4];
    const float* W_gcn  = (const float*)d_in[5];
    const float* b_gcn  = (const float*)d_in[6];
    const float* g1     = (const float*)d_in[7];
    const float* be1    = (const float*)d_in[8];
    const float* W_lin1 = (const float*)d_in[9];
    const float* b_lin1 = (const float*)d_in[10];
    const float* g2     = (const float*)d_in[11];
    const float* be2    = (const float*)d_in[12];
    const float* W_lin2 = (const float*)d_in[13];
    const float* b_lin2 = (const float*)d_in[14];
    const float* g3     = (const float*)d_in[15];
    const float* be3    = (const float*)d_in[16];
    const float* W_fc1  = (const float*)d_in[17];
    const float* b_fc1  = (const float*)d_in[18];
    const float* g4     = (const float*)d_in[19];
    const float* be4    = (const float*)d_in[20];
    const float* W_fc2  = (const float*)d_in[21];
    const float* b_fc2  = (const float*)d_in[22];
    const float* g5     = (const float*)d_in[23];
    const float* be5    = (const float*)d_in[24];
    const float* W_fc3  = (const float*)d_in[25];
    const float* b_fc3  = (const float*)d_in[26];

    float* ws = (float*)d_ws;
    int*   ghist  = (int*)(ws + WS_GHIST);
    float* bnagg  = ws + WS_BNAGG;
    float* stats1 = ws + WS_STATS1;
    float* stats2 = ws + WS_STATS2;
    float* stats4 = ws + WS_STATS4;
    float* stats5 = ws + WS_STATS5;
    int*   gbase  = (int*)(ws + WS_GBASE);
    int*   gcur   = (int*)(ws + WS_GCUR);
    int*   gstart = (int*)(ws + WS_GSTART);
    float* dis    = ws + WS_DIS;
    int*   rowptr = (int*)(ws + WS_ROWPTR);
    unsigned int* packed = (unsigned int*)(ws + WS_PACKED);
    int*   csrc   = (int*)(ws + WS_CSRC);
    float* scale1 = ws + WS_SCALE1;
    float* shift1 = ws + WS_SHIFT1;
    float* aggx   = ws + WS_AGGX;
    float* agg    = ws + WS_AGG;
    float* pooled = ws + WS_POOLED;
    float* t1     = ws + WS_T1;
    float* t2     = ws + WS_T2;
    float* t4     = ws + WS_T4;
    float* t5     = ws + WS_T5;
    float* out    = (float*)d_out;

    zero_kernel<<<6, 256, 0, stream>>>(ws, WS_ZTOTAL);
    hist_kernel<<<256, 256, 0, stream>>>(ei + N_EDGES, ghist);
    scan_kernel<<<1, 256, 0, stream>>>(ghist, gbase, gcur);
    bin_kernel<<<BIN_BLOCKS, 1024, 0, stream>>>(ei, gcur, packed);
    csr_build_kernel<<<NBUCK, 256, 0, stream>>>(packed, gbase, ghist, rowptr, csrc, dis);
    gather_kernel<<<(N_NODES * 64 + 255) / 256, 256, 0, stream>>>(gnn_x, rowptr, csrc, dis, aggx);
    gemm_agg_kernel<<<N_NODES / 16, 256, 0, stream>>>(aggx, W_gcn, b_gcn, agg);
    bnagg_stats_kernel<<<512, 256, 0, stream>>>(agg, bnagg);
    bn1_fold_kernel<<<1, 128, 0, stream>>>(bnagg, g1, be1, scale1, shift1);
    graph_bounds_kernel<<<1, 1024, 0, stream>>>(gbatch, gstart);
    pool_gather_kernel<<<(N_GRAPHS * 64 + 255) / 256, 256, 0, stream>>>(agg, gstart, scale1, shift1, pooled);
    lin1_kernel<<<256, 256, 0, stream>>>(pooled, W_lin1, b_lin1, t1, stats1);
    lin2_kernel<<<256, 256, 0, stream>>>(t1, stats1, g2, be2, W_lin2, b_lin2, t2, stats2);
    fc1_kernel<<<256, 1024, 0, stream>>>(x, masks, t2, stats2, g3, be3, W_fc1, b_fc1, t4, stats4);
    fc2_kernel<<<256, 256, 0, stream>>>(t4, stats4, g4, be4, W_fc2, b_fc2, t5, stats5);
    fc3_kernel<<<4, 256, 0, stream>>>(t5, stats5, g5, be5, W_fc3, b_fc3, out);
}

// Round 5
// 272.093 us; speedup vs baseline: 2.8445x; 1.0853x over previous
//
#include <hip/hip_runtime.h>
#include <hip/hip_bf16.h>

#define N_NODES 100000
#define N_EDGES 1600000
#define N_GRAPHS 1024
#define BSZ 1024
#define EPS 1e-5f

#define NBUCK 256
#define BUCKW 391          // ceil(100000/256)
#define BCAP  8192         // static per-bucket edge capacity (mean 6250, sd 79)
#define SRC_MASK 0x1FFFF   // 17 bits for src (<131072)
#define BIN_CHUNK 8192
#define BIN_BLOCKS 196     // ceil(1600000/8192)

// ---------------- workspace layout (4-byte units) ----------------
// zeroed-every-call region:
#define WS_BNAGG   0          // 256 (sum[128], sumsq[128]) of agg
#define WS_STATS1  256        // 128
#define WS_STATS2  384        // 128
#define WS_STATS4  512        // 512
#define WS_STATS5  1024       // 128
#define WS_ZTOTAL  1152
// written-before-read region:
#define WS_GCUR    1152       // 256 int (init to b*BCAP by prep)
#define WS_SCALE1  1408       // 128
#define WS_SHIFT1  1536       // 128
#define WS_GSTART  1664       // 1025 int (pad to 2692)
#define WS_DIS     2692       // 100000 float
#define WS_ROWPTR  102692     // 100000 int (absolute start into csrc)
#define WS_ROWLEN  202692     // 100000 int
// union region: AGG aliases {PACKED, CSRC, XH} (all dead before gemm_agg writes AGG)
#define WS_AGG     302692     // 100000*128 -> ends 13102692
#define WS_PACKED  302692     // 256*8192 u32 -> 2399844
#define WS_CSRC    2399844    // 256*8192 int -> 4496996
#define WS_XH      4496996    // 100000*64 ushort = 3200000 words -> 7696996
#define WS_AGGX    13102692   // 100000*64 -> 19502692
#define WS_POOLED  19502692   // 1024*128 -> 19633764
#define WS_T1      19633764   // 1024*64 -> 19699300
#define WS_T2      19699300   // 1024*64 -> 19764836
#define WS_T4      19764836   // 1024*256 -> 20026980
#define WS_T5      20026980   // 1024*64 -> 20092516
// total = 20092516 words = ~80.4 MB

__device__ inline unsigned short f2bf(float f) {
    unsigned int u = __float_as_uint(f);
    return (unsigned short)((u + 0x7FFFu + ((u >> 16) & 1u)) >> 16);
}

// block 0: zero stats; block 1: init gcur; blocks 2-5: graph bounds binary search
__global__ __launch_bounds__(256) void prep_kernel(float* __restrict__ ws,
                                                   const int* __restrict__ gbatch) {
    int b = blockIdx.x, tid = threadIdx.x;
    if (b == 0) {
        for (int i = tid; i < WS_ZTOTAL; i += 256) ws[i] = 0.0f;
    } else if (b == 1) {
        ((int*)(ws + WS_GCUR))[tid] = tid * BCAP;
    } else {
        int g = (b - 2) * 256 + tid;
        int lo = 0, hi = N_NODES;
        while (lo < hi) {
            int mid = (lo + hi) >> 1;
            if (gbatch[mid] < g) lo = mid + 1; else hi = mid;
        }
        int* gstart = (int*)(ws + WS_GSTART);
        gstart[g] = lo;
        if (g == 0) gstart[N_GRAPHS] = N_NODES;
    }
}

// fp32 -> bf16 copy of gnn_x
__global__ __launch_bounds__(256) void cvt_kernel(const float* __restrict__ x,
                                                  unsigned short* __restrict__ xh) {
    int i = blockIdx.x * 256 + threadIdx.x;   // i < 1.6M, 4 elems each
    float4 f = ((const float4*)x)[i];
    ushort4 h;
    h.x = f2bf(f.x); h.y = f2bf(f.y); h.z = f2bf(f.z); h.w = f2bf(f.w);
    ((ushort4*)xh)[i] = h;
}

// bin edges into 256 coarse dst-buckets (static BCAP stride) with LDS staging
__global__ __launch_bounds__(1024) void bin_kernel(const int* __restrict__ ei,
                                                   int* __restrict__ gcursor,
                                                   unsigned int* __restrict__ packed) {
    __shared__ unsigned int stage[BIN_CHUNK];   // 32KB
    __shared__ int lh[NBUCK], lbase[NBUCK], lcur[NBUCK], gb[NBUCK];
    const int* src = ei;
    const int* dst = ei + N_EDGES;
    int tid = threadIdx.x;
    int base = blockIdx.x * BIN_CHUNK;
    int n = min(BIN_CHUNK, N_EDGES - base);
    if (tid < NBUCK) lh[tid] = 0;
    __syncthreads();
    for (int i = tid; i < n; i += 1024)
        atomicAdd(&lh[dst[base + i] / BUCKW], 1);
    __syncthreads();
    if (tid < NBUCK) lbase[tid] = lh[tid];
    __syncthreads();
    for (int off = 1; off < NBUCK; off <<= 1) {
        int t = (tid < NBUCK && tid >= off) ? lbase[tid - off] : 0;
        __syncthreads();
        if (tid < NBUCK) lbase[tid] += t;
        __syncthreads();
    }
    if (tid < NBUCK) {
        int excl = lbase[tid] - lh[tid];
        lbase[tid] = excl;
        lcur[tid] = excl;
        gb[tid] = atomicAdd(&gcursor[tid], lh[tid]);
    }
    __syncthreads();
    for (int i = tid; i < n; i += 1024) {
        int d = dst[base + i];
        int s = src[base + i];
        int bk = d / BUCKW;
        int dl = d - bk * BUCKW;
        int slot = atomicAdd(&lcur[bk], 1);
        stage[slot] = ((unsigned int)dl << 17) | (unsigned int)s;
    }
    __syncthreads();
    int wid = tid >> 6, lane = tid & 63;
    for (int bk = wid; bk < NBUCK; bk += 16) {
        int lo = lbase[bk], go = gb[bk];
        int len = min(lh[bk], (bk + 1) * BCAP - go);  // overflow clamp (never expected)
        for (int j = lane; j < len; j += 64)
            packed[go + j] = stage[lo + j];
    }
}

// per-bucket: exact CSR (sorted in LDS, coalesced write) + rowptr/rowlen + dis
__global__ __launch_bounds__(256) void csr_build_kernel(const unsigned int* __restrict__ packed,
                                                        const int* __restrict__ gcur,
                                                        int* __restrict__ rowptr,
                                                        int* __restrict__ rowlen,
                                                        int* __restrict__ csrc,
                                                        float* __restrict__ dis) {
    __shared__ int dcnt[BUCKW];       // deg histogram, then excl scan
    __shared__ int lcur[BUCKW];       // scatter cursors
    __shared__ int stage[BCAP];       // 32KB sorted srcs
    int b = blockIdx.x, tid = threadIdx.x;
    int e0 = b * BCAP;
    int ecnt = min(gcur[b] - e0, BCAP);
    int nbase = b * BUCKW;
    int nmax = min(BUCKW, N_NODES - nbase);
    for (int i = tid; i < BUCKW; i += 256) dcnt[i] = 0;
    __syncthreads();
    for (int i = tid; i < ecnt; i += 256)
        atomicAdd(&dcnt[packed[e0 + i] >> 17], 1);
    __syncthreads();
    for (int i = tid; i < nmax; i += 256) {
        dis[nbase + i] = rsqrtf((float)dcnt[i] + 1.0f);
        rowlen[nbase + i] = dcnt[i];
    }
    __syncthreads();
    // exclusive scan of dcnt by wave 0 (7 chunks of 64)
    if (tid < 64) {
        int lane = tid;
        int run = 0;
        for (int c = 0; c < BUCKW; c += 64) {
            int idx = c + lane;
            int v = (idx < BUCKW) ? dcnt[idx] : 0;
            int inc = v;
#pragma unroll
            for (int off = 1; off < 64; off <<= 1) {
                int t = __shfl_up(inc, off);
                if (lane >= off) inc += t;
            }
            if (idx < BUCKW) {
                int excl = run + inc - v;
                dcnt[idx] = excl;
                lcur[idx] = excl;
            }
            run += __shfl(inc, 63);
        }
    }
    __syncthreads();
    for (int i = tid; i < nmax; i += 256)
        rowptr[nbase + i] = e0 + dcnt[i];
    for (int i = tid; i < ecnt; i += 256) {
        unsigned int r = packed[e0 + i];
        int slot = atomicAdd(&lcur[r >> 17], 1);
        stage[slot] = (int)(r & SRC_MASK);
    }
    __syncthreads();
    for (int i = tid; i < ecnt; i += 256) csrc[e0 + i] = stage[i];
}

// aggx[n] = x[n]*dis[n]^2 + sum_{s in in(n)} xh[s]*dis[s]*dis[n]
// one wave per node, 8-deep pipelined gather; neighbor rows read as bf16
__global__ __launch_bounds__(256) void gather_kernel(const float* __restrict__ x,
                                                     const unsigned short* __restrict__ xh,
                                                     const int* __restrict__ rowptr,
                                                     const int* __restrict__ rowlen,
                                                     const int* __restrict__ csrc,
                                                     const float* __restrict__ dis,
                                                     float* __restrict__ aggx) {
    int wid = (blockIdx.x * 256 + threadIdx.x) >> 6;
    int lane = threadIdx.x & 63;
    if (wid >= N_NODES) return;
    int start = rowptr[wid];
    int len = rowlen[wid];
    float dd = dis[wid];
    float acc = x[(size_t)wid * 64 + lane] * dd * dd;
    for (int j0 = 0; j0 < len; j0 += 64) {
        int cnt = min(64, len - j0);
        int sv = 0;
        float wv = 0.f;
        if (lane < cnt) {
            sv = csrc[start + j0 + lane];
            wv = dis[sv] * dd;
        }
        int iters = (cnt + 7) & ~7;
        for (int k = 0; k < iters; k += 8) {
            int s[8]; float w[8], v[8];
#pragma unroll
            for (int u = 0; u < 8; ++u) {
                s[u] = __shfl(sv, k + u);
                w[u] = __shfl(wv, k + u);
            }
#pragma unroll
            for (int u = 0; u < 8; ++u)
                v[u] = __uint_as_float((unsigned int)xh[(size_t)s[u] * 64 + lane] << 16);
#pragma unroll
            for (int u = 0; u < 8; ++u) acc = fmaf(v[u], w[u], acc);
        }
    }
    aggx[(size_t)wid * 64 + lane] = acc;
}

// agg[100000,128] = aggx[100000,64] @ W_gcn[64,128] + b_gcn
__global__ __launch_bounds__(256) void gemm_agg_kernel(const float* __restrict__ A,
                                                       const float* __restrict__ W,
                                                       const float* __restrict__ bias,
                                                       float* __restrict__ AGG) {
    __shared__ float Ws[64 * 128];
    __shared__ float As[16 * 64];
    int tid = threadIdx.x;
    const float4* W4 = (const float4*)W;
    float4* Ws4 = (float4*)Ws;
#pragma unroll
    for (int i = 0; i < 8; ++i) Ws4[tid + i * 256] = W4[tid + i * 256];
    int row0 = blockIdx.x * 16;
    ((float4*)As)[tid] = ((const float4*)(A + (size_t)row0 * 64))[tid];
    __syncthreads();
    int tx = tid & 31;
    int ty = tid >> 5;
    int r0 = ty * 2;
    float4 bb = ((const float4*)bias)[tx];
    float acc[2][4] = {{bb.x, bb.y, bb.z, bb.w}, {bb.x, bb.y, bb.z, bb.w}};
#pragma unroll
    for (int k = 0; k < 64; ++k) {
        float a0 = As[r0 * 64 + k];
        float a1 = As[(r0 + 1) * 64 + k];
        float4 w = Ws4[k * 32 + tx];
        acc[0][0] += a0 * w.x; acc[0][1] += a0 * w.y; acc[0][2] += a0 * w.z; acc[0][3] += a0 * w.w;
        acc[1][0] += a1 * w.x; acc[1][1] += a1 * w.y; acc[1][2] += a1 * w.z; acc[1][3] += a1 * w.w;
    }
#pragma unroll
    for (int rr = 0; rr < 2; ++rr) {
        float4 v = make_float4(acc[rr][0], acc[rr][1], acc[rr][2], acc[rr][3]);
        ((float4*)(AGG + (size_t)(row0 + r0 + rr) * 128))[tx] = v;
    }
}

__global__ __launch_bounds__(256) void bnagg_stats_kernel(const float* __restrict__ agg,
                                                          float* __restrict__ stats) {
    __shared__ float4 ls[256];
    int tid = threadIdx.x;
    int lane = tid & 63;
    int grp = tid >> 6;
    int f = lane * 2;
    float2 s = {0.f, 0.f}, sq = {0.f, 0.f};
    for (int r = blockIdx.x * 4 + grp; r < N_NODES; r += gridDim.x * 4) {
        float2 a = *(const float2*)(agg + (size_t)r * 128 + f);
        s.x += a.x; s.y += a.y;
        sq.x += a.x * a.x; sq.y += a.y * a.y;
    }
    ls[tid] = make_float4(s.x, s.y, sq.x, sq.y);
    __syncthreads();
    if (tid < 64) {
        float4 v = ls[tid];
        float4 b = ls[tid + 64], c = ls[tid + 128], d = ls[tid + 192];
        v.x += b.x + c.x + d.x;
        v.y += b.y + c.y + d.y;
        v.z += b.z + c.z + d.z;
        v.w += b.w + c.w + d.w;
        unsafeAtomicAdd(&stats[f], v.x);
        unsafeAtomicAdd(&stats[f + 1], v.y);
        unsafeAtomicAdd(&stats[128 + f], v.z);
        unsafeAtomicAdd(&stats[128 + f + 1], v.w);
    }
}

__global__ void bn1_fold_kernel(const float* __restrict__ stats, const float* __restrict__ g1,
                                const float* __restrict__ be1, float* __restrict__ scale1,
                                float* __restrict__ shift1) {
    int f = threadIdx.x;
    float m = stats[f] * (1.0f / N_NODES);
    float var = stats[128 + f] * (1.0f / N_NODES) - m * m;
    float sc = g1[f] * rsqrtf(var + EPS);
    scale1[f] = sc;
    shift1[f] = be1[f] - m * sc;
}

// pooled[g] = mean over rows of relu(agg*scale1+shift1); one wave per graph
__global__ __launch_bounds__(256) void pool_gather_kernel(const float* __restrict__ agg,
                                                          const int* __restrict__ gstart,
                                                          const float* __restrict__ scale1,
                                                          const float* __restrict__ shift1,
                                                          float* __restrict__ pooled) {
    int g = (blockIdx.x * 256 + threadIdx.x) >> 6;
    int lane = threadIdx.x & 63;
    if (g >= N_GRAPHS) return;
    int r0 = gstart[g], r1 = gstart[g + 1];
    int f = lane * 2;
    float2 sc = *(const float2*)(scale1 + f);
    float2 sh = *(const float2*)(shift1 + f);
    float2 acc = {0.f, 0.f};
    for (int r = r0; r < r1; ++r) {
        float2 a = *(const float2*)(agg + (size_t)r * 128 + f);
        acc.x += fmaxf(a.x * sc.x + sh.x, 0.f);
        acc.y += fmaxf(a.y * sc.y + sh.y, 0.f);
    }
    float inv = 1.0f / fmaxf((float)(r1 - r0), 1.0f);
    float2 o; o.x = acc.x * inv; o.y = acc.y * inv;
    *(float2*)(pooled + (size_t)g * 128 + f) = o;
}

// t1 = pooled @ W_lin1 + b ; stats1 += (sum, sumsq)
__global__ __launch_bounds__(256) void lin1_kernel(const float* __restrict__ pooled,
                                                   const float* __restrict__ W,
                                                   const float* __restrict__ bias,
                                                   float* __restrict__ t1,
                                                   float* __restrict__ stats1) {
    __shared__ float ls[256], ls2[256];
    int tid = threadIdx.x;
    int r = blockIdx.x * 4 + (tid >> 6);
    int c = tid & 63;
    float acc = bias[c];
    const float* srow = pooled + (size_t)r * 128;
#pragma unroll 8
    for (int k = 0; k < 128; ++k)
        acc += srow[k] * W[k * 64 + c];
    t1[r * 64 + c] = acc;
    ls[tid] = acc; ls2[tid] = acc * acc;
    __syncthreads();
    if (tid < 64) {
        float s = ls[tid] + ls[tid + 64] + ls[tid + 128] + ls[tid + 192];
        float q = ls2[tid] + ls2[tid + 64] + ls2[tid + 128] + ls2[tid + 192];
        unsafeAtomicAdd(&stats1[c], s);
        unsafeAtomicAdd(&stats1[64 + c], q);
    }
}

// t2 = relu(bn(t1; g2,be2)) @ W_lin2 + b ; stats2
__global__ __launch_bounds__(256) void lin2_kernel(const float* __restrict__ t1,
                                                   const float* __restrict__ stats1,
                                                   const float* __restrict__ g,
                                                   const float* __restrict__ be,
                                                   const float* __restrict__ W,
                                                   const float* __restrict__ bias,
                                                   float* __restrict__ t2,
                                                   float* __restrict__ stats2) {
    __shared__ float sc[64], sh[64];
    __shared__ float ls[256], ls2[256];
    int tid = threadIdx.x;
    if (tid < 64) {
        float m = stats1[tid] * (1.0f / BSZ);
        float var = stats1[64 + tid] * (1.0f / BSZ) - m * m;
        float s = g[tid] * rsqrtf(var + EPS);
        sc[tid] = s; sh[tid] = be[tid] - m * s;
    }
    __syncthreads();
    int r = blockIdx.x * 4 + (tid >> 6);
    int c = tid & 63;
    float acc = bias[c];
    const float* row = t1 + (size_t)r * 64;
#pragma unroll 8
    for (int k = 0; k < 64; ++k) {
        float z = fmaxf(row[k] * sc[k] + sh[k], 0.f);
        acc += z * W[k * 64 + c];
    }
    t2[r * 64 + c] = acc;
    ls[tid] = acc; ls2[tid] = acc * acc;
    __syncthreads();
    if (tid < 64) {
        float s = ls[tid] + ls[tid + 64] + ls[tid + 128] + ls[tid + 192];
        float q = ls2[tid] + ls2[tid + 64] + ls2[tid + 128] + ls2[tid + 192];
        unsafeAtomicAdd(&stats2[c], s);
        unsafeAtomicAdd(&stats2[64 + c], q);
    }
}

// t4 = concat(x, bn(t2;g3,be3)[masks]) @ W_fc1 + b ; stats4
__global__ __launch_bounds__(1024) void fc1_kernel(const float* __restrict__ x,
                                                   const int* __restrict__ masks,
                                                   const float* __restrict__ t2,
                                                   const float* __restrict__ stats2,
                                                   const float* __restrict__ g3,
                                                   const float* __restrict__ be3,
                                                   const float* __restrict__ W,
                                                   const float* __restrict__ bias,
                                                   float* __restrict__ t4,
                                                   float* __restrict__ stats4) {
    __shared__ float sc[64], sh[64];
    __shared__ float cat[4][128];
    __shared__ float ls[1024], ls2[1024];
    int tid = threadIdx.x;
    if (tid < 64) {
        float m = stats2[tid] * (1.0f / BSZ);
        float var = stats2[64 + tid] * (1.0f / BSZ) - m * m;
        float s = g3[tid] * rsqrtf(var + EPS);
        sc[tid] = s; sh[tid] = be3[tid] - m * s;
    }
    __syncthreads();
    int r0 = blockIdx.x * 4;
    if (tid < 512) {
        int i = tid >> 7;
        int k = tid & 127;
        int r = r0 + i;
        float v;
        if (k < 64) {
            v = x[r * 64 + k];
        } else {
            int mrow = masks[r];
            int kk = k - 64;
            v = t2[mrow * 64 + kk] * sc[kk] + sh[kk];
        }
        cat[i][k] = v;
    }
    __syncthreads();
    int i = tid >> 8;
    int c = tid & 255;
    float acc = bias[c];
#pragma unroll 8
    for (int k = 0; k < 128; ++k)
        acc += cat[i][k] * W[k * 256 + c];
    t4[(size_t)(r0 + i) * 256 + c] = acc;
    ls[tid] = acc; ls2[tid] = acc * acc;
    __syncthreads();
    if (tid < 256) {
        float s = ls[tid] + ls[tid + 256] + ls[tid + 512] + ls[tid + 768];
        float q = ls2[tid] + ls2[tid + 256] + ls2[tid + 512] + ls2[tid + 768];
        unsafeAtomicAdd(&stats4[c], s);
        unsafeAtomicAdd(&stats4[256 + c], q);
    }
}

// t5 = (relu(bn(t4;g4,be4))^2) @ W_fc2 + b ; stats5
__global__ __launch_bounds__(256) void fc2_kernel(const float* __restrict__ t4,
                                                  const float* __restrict__ stats4,
                                                  const float* __restrict__ g4,
                                                  const float* __restrict__ be4,
                                                  const float* __restrict__ W,
                                                  const float* __restrict__ bias,
                                                  float* __restrict__ t5,
                                                  float* __restrict__ stats5) {
    __shared__ float sc[256], sh[256];
    __shared__ float ls[256], ls2[256];
    int tid = threadIdx.x;
    {
        float m = stats4[tid] * (1.0f / BSZ);
        float var = stats4[256 + tid] * (1.0f / BSZ) - m * m;
        float s = g4[tid] * rsqrtf(var + EPS);
        sc[tid] = s; sh[tid] = be4[tid] - m * s;
    }
    __syncthreads();
    int r = blockIdx.x * 4 + (tid >> 6);
    int c = tid & 63;
    float acc = bias[c];
    const float* row = t4 + (size_t)r * 256;
#pragma unroll 8
    for (int k = 0; k < 256; ++k) {
        float z = fmaxf(row[k] * sc[k] + sh[k], 0.f);
        z *= z;
        acc += z * W[k * 64 + c];
    }
    t5[r * 64 + c] = acc;
    ls[tid] = acc; ls2[tid] = acc * acc;
    __syncthreads();
    if (tid < 64) {
        float s = ls[tid] + ls[tid + 64] + ls[tid + 128] + ls[tid + 192];
        float q = ls2[tid] + ls2[tid + 64] + ls2[tid + 128] + ls2[tid + 192];
        unsafeAtomicAdd(&stats5[c], s);
        unsafeAtomicAdd(&stats5[64 + c], q);
    }
}

// out = ((relu(bn(t5;g5,be5)))^4) @ W_fc3 + b
__global__ __launch_bounds__(256) void fc3_kernel(const float* __restrict__ t5,
                                                  const float* __restrict__ stats5,
                                                  const float* __restrict__ g5,
                                                  const float* __restrict__ be5,
                                                  const float* __restrict__ W,
                                                  const float* __restrict__ bias,
                                                  float* __restrict__ out) {
    __shared__ float sc[64], sh[64];
    int tid = threadIdx.x;
    if (tid < 64) {
        float m = stats5[tid] * (1.0f / BSZ);
        float var = stats5[64 + tid] * (1.0f / BSZ) - m * m;
        float s = g5[tid] * rsqrtf(var + EPS);
        sc[tid] = s; sh[tid] = be5[tid] - m * s;
    }
    __syncthreads();
    int r = blockIdx.x * 256 + tid;
    float acc = bias[0];
    const float* row = t5 + (size_t)r * 64;
#pragma unroll
    for (int k = 0; k < 64; ++k) {
        float z = fmaxf(row[k] * sc[k] + sh[k], 0.f);
        z = z * z;
        z = z * z;
        acc += z * W[k];
    }
    out[r] = acc;
}

extern "C" void kernel_launch(void* const* d_in, const int* in_sizes, int n_in,
                              void* d_out, int out_size, void* d_ws, size_t ws_size,
                              hipStream_t stream) {
    const float* x      = (const float*)d_in[0];
    const int*   masks  = (const int*)d_in[1];
    const float* gnn_x  = (const float*)d_in[2];
    const int*   ei     = (const int*)d_in[3];
    const int*   gbatch = (const int*)d_in[4];
    const float* W_gcn  = (const float*)d_in[5];
    const float* b_gcn  = (const float*)d_in[6];
    const float* g1     = (const float*)d_in[7];
    const float* be1    = (const float*)d_in[8];
    const float* W_lin1 = (const float*)d_in[9];
    const float* b_lin1 = (const float*)d_in[10];
    const float* g2     = (const float*)d_in[11];
    const float* be2    = (const float*)d_in[12];
    const float* W_lin2 = (const float*)d_in[13];
    const float* b_lin2 = (const float*)d_in[14];
    const float* g3     = (const float*)d_in[15];
    const float* be3    = (const float*)d_in[16];
    const float* W_fc1  = (const float*)d_in[17];
    const float* b_fc1  = (const float*)d_in[18];
    const float* g4     = (const float*)d_in[19];
    const float* be4    = (const float*)d_in[20];
    const float* W_fc2  = (const float*)d_in[21];
    const float* b_fc2  = (const float*)d_in[22];
    const float* g5     = (const float*)d_in[23];
    const float* be5    = (const float*)d_in[24];
    const float* W_fc3  = (const float*)d_in[25];
    const float* b_fc3  = (const float*)d_in[26];

    float* ws = (float*)d_ws;
    float* bnagg  = ws + WS_BNAGG;
    float* stats1 = ws + WS_STATS1;
    float* stats2 = ws + WS_STATS2;
    float* stats4 = ws + WS_STATS4;
    float* stats5 = ws + WS_STATS5;
    int*   gcur   = (int*)(ws + WS_GCUR);
    float* scale1 = ws + WS_SCALE1;
    float* shift1 = ws + WS_SHIFT1;
    int*   gstart = (int*)(ws + WS_GSTART);
    float* dis    = ws + WS_DIS;
    int*   rowptr = (int*)(ws + WS_ROWPTR);
    int*   rowlen = (int*)(ws + WS_ROWLEN);
    float* agg    = ws + WS_AGG;
    unsigned int* packed = (unsigned int*)(ws + WS_PACKED);
    int*   csrc   = (int*)(ws + WS_CSRC);
    unsigned short* xh = (unsigned short*)(ws + WS_XH);
    float* aggx   = ws + WS_AGGX;
    float* pooled = ws + WS_POOLED;
    float* t1     = ws + WS_T1;
    float* t2     = ws + WS_T2;
    float* t4     = ws + WS_T4;
    float* t5     = ws + WS_T5;
    float* out    = (float*)d_out;

    prep_kernel<<<6, 256, 0, stream>>>(ws, gbatch);
    cvt_kernel<<<N_NODES * 64 / 4 / 256, 256, 0, stream>>>(gnn_x, xh);
    bin_kernel<<<BIN_BLOCKS, 1024, 0, stream>>>(ei, gcur, packed);
    csr_build_kernel<<<NBUCK, 256, 0, stream>>>(packed, gcur, rowptr, rowlen, csrc, dis);
    gather_kernel<<<(N_NODES * 64 + 255) / 256, 256, 0, stream>>>(gnn_x, xh, rowptr, rowlen, csrc, dis, aggx);
    gemm_agg_kernel<<<N_NODES / 16, 256, 0, stream>>>(aggx, W_gcn, b_gcn, agg);
    bnagg_stats_kernel<<<512, 256, 0, stream>>>(agg, bnagg);
    bn1_fold_kernel<<<1, 128, 0, stream>>>(bnagg, g1, be1, scale1, shift1);
    pool_gather_kernel<<<(N_GRAPHS * 64 + 255) / 256, 256, 0, stream>>>(agg, gstart, scale1, shift1, pooled);
    lin1_kernel<<<256, 256, 0, stream>>>(pooled, W_lin1, b_lin1, t1, stats1);
    lin2_kernel<<<256, 256, 0, stream>>>(t1, stats1, g2, be2, W_lin2, b_lin2, t2, stats2);
    fc1_kernel<<<256, 1024, 0, stream>>>(x, masks, t2, stats2, g3, be3, W_fc1, b_fc1, t4, stats4);
    fc2_kernel<<<256, 256, 0, stream>>>(t4, stats4, g4, be4, W_fc2, b_fc2, t5, stats5);
    fc3_kernel<<<4, 256, 0, stream>>>(t5, stats5, g5, be5, W_fc3, b_fc3, out);
}